// Round 10
// baseline (1640.924 us; speedup 1.0000x reference)
//
#include <hip/hip_runtime.h>
#include <hip/hip_fp16.h>

#define N_VAR 256
#define M_CON 512
#define BATCH 64
#define SIGMA_C 1e-6f
#define RHO_C 0.1f
#define ALPHA_C 1.6f
#define NITERS 500

typedef _Float16 f16x8 __attribute__((ext_vector_type(8)));
typedef float f32x4 __attribute__((ext_vector_type(4)));

// ---------------------------------------------------------------------------
// K1: transpose A [512][256] -> At [256][512] per batch
// ---------------------------------------------------------------------------
__global__ __launch_bounds__(256) void k_transpose(const float* __restrict__ A,
                                                   float* __restrict__ At) {
  __shared__ float tile[32][33];
  int b = blockIdx.z;
  int n0 = blockIdx.x * 32;
  int m0 = blockIdx.y * 32;
  const float* Ab = A + (size_t)b * (M_CON * N_VAR);
  float* Atb = At + (size_t)b * (M_CON * N_VAR);
  int tx = threadIdx.x, ty = threadIdx.y;  // (32, 8)
#pragma unroll
  for (int j = 0; j < 32; j += 8)
    tile[ty + j][tx] = Ab[(size_t)(m0 + ty + j) * N_VAR + n0 + tx];
  __syncthreads();
#pragma unroll
  for (int j = 0; j < 32; j += 8)
    Atb[(size_t)(n0 + ty + j) * M_CON + m0 + tx] = tile[tx][ty + j];
}

// ---------------------------------------------------------------------------
// K2: batched NT GEMM  C[i][j] = alpha * sum_k X[i][k]*Y[j][k]  (+ diag)
// packC=0: fp32 C.  packC=2: split-fp16 C into Ch/Ce (row-major, J=256).
// ---------------------------------------------------------------------------
__global__ __launch_bounds__(256) void k_ntgemm(
    const float* __restrict__ X, const float* __restrict__ Y,
    float* __restrict__ C, float* __restrict__ C2, int I, int J, int K,
    long long bsX, long long bsY, long long bsC, float alpha,
    const float* __restrict__ diagv, int tilesJ, int packC) {
  int b = blockIdx.y;
  int ti = blockIdx.x / tilesJ, tj = blockIdx.x % tilesJ;
  int i0 = ti * 128, j0 = tj * 128;
  const float* Xb = X + (size_t)b * bsX;
  const float* Yb = Y + (size_t)b * bsY;
  __shared__ float Xs[16][128];
  __shared__ float Ys[16][128];
  int tid = threadIdx.x;
  int tx = tid & 15, ty = tid >> 4;
  float acc[8][8];
#pragma unroll
  for (int r = 0; r < 8; ++r)
#pragma unroll
    for (int c = 0; c < 8; ++c) acc[r][c] = 0.0f;

  for (int kk = 0; kk < K; kk += 16) {
#pragma unroll
    for (int v = 0; v < 2; ++v) {
      int idx = v * 256 + tid;
      int row = idx >> 2;
      int k4 = (idx & 3) * 4;
      float4 gx = *(const float4*)(Xb + (size_t)(i0 + row) * K + kk + k4);
      Xs[k4 + 0][row] = gx.x; Xs[k4 + 1][row] = gx.y;
      Xs[k4 + 2][row] = gx.z; Xs[k4 + 3][row] = gx.w;
      float4 gy = *(const float4*)(Yb + (size_t)(j0 + row) * K + kk + k4);
      Ys[k4 + 0][row] = gy.x; Ys[k4 + 1][row] = gy.y;
      Ys[k4 + 2][row] = gy.z; Ys[k4 + 3][row] = gy.w;
    }
    __syncthreads();
#pragma unroll
    for (int k = 0; k < 16; ++k) {
      float xr[8], yr[8];
      *(float4*)&xr[0] = *(float4*)&Xs[k][ty * 8];
      *(float4*)&xr[4] = *(float4*)&Xs[k][ty * 8 + 4];
      *(float4*)&yr[0] = *(float4*)&Ys[k][tx * 8];
      *(float4*)&yr[4] = *(float4*)&Ys[k][tx * 8 + 4];
#pragma unroll
      for (int r = 0; r < 8; ++r)
#pragma unroll
        for (int c = 0; c < 8; ++c) acc[r][c] += xr[r] * yr[c];
    }
    __syncthreads();
  }
  if (packC == 2) {
    unsigned* Ch = (unsigned*)C + (size_t)b * 65536;   // 512x256 halves
    unsigned* Ce = (unsigned*)C2 + (size_t)b * 65536;
#pragma unroll
    for (int r = 0; r < 8; ++r) {
      int gi = i0 + ty * 8 + r;
#pragma unroll
      for (int c = 0; c < 8; c += 2) {
        int gj = j0 + tx * 8 + c;
        float v0 = acc[r][c] * alpha, v1 = acc[r][c + 1] * alpha;
        __half2 hh = __floats2half2_rn(v0, v1);
        float2 fb = __half22float2(hh);
        __half2 he = __floats2half2_rn((v0 - fb.x) * 256.0f,
                                       (v1 - fb.y) * 256.0f);
        int idx = gi * 128 + (gj >> 1);
        Ch[idx] = *(unsigned*)&hh;
        Ce[idx] = *(unsigned*)&he;
      }
    }
    return;
  }
  float* Cb = C + (size_t)b * bsC;
#pragma unroll
  for (int r = 0; r < 8; ++r) {
    int gi = i0 + ty * 8 + r;
#pragma unroll
    for (int c = 0; c < 8; ++c) {
      int gj = j0 + tx * 8 + c;
      float val = acc[r][c] * alpha;
      if (diagv != nullptr && gi == gj) val += diagv[(size_t)b * N_VAR + gi] + SIGMA_C;
      Cb[(size_t)gi * J + gj] = val;
    }
  }
}

// ---------------------------------------------------------------------------
// K2b: split-fp16 cast of Av: ah = half(a), ae = half((a - float(ah))*256)
// ---------------------------------------------------------------------------
__global__ __launch_bounds__(256) void k_cast_split(
    const float* __restrict__ in, unsigned* __restrict__ oh,
    unsigned* __restrict__ oe, int n4) {
  int i = blockIdx.x * 256 + threadIdx.x;
  if (i >= n4) return;
  float4 v = ((const float4*)in)[i];
  __half2 h01 = __floats2half2_rn(v.x, v.y);
  __half2 h23 = __floats2half2_rn(v.z, v.w);
  float2 f01 = __half22float2(h01);
  float2 f23 = __half22float2(h23);
  __half2 e01 = __floats2half2_rn((v.x - f01.x) * 256.0f, (v.y - f01.y) * 256.0f);
  __half2 e23 = __floats2half2_rn((v.z - f23.x) * 256.0f, (v.w - f23.y) * 256.0f);
  uint2 uh; uh.x = *(unsigned*)&h01; uh.y = *(unsigned*)&h23;
  uint2 ue; ue.x = *(unsigned*)&e01; ue.y = *(unsigned*)&e23;
  ((uint2*)oh)[i] = uh;
  ((uint2*)oe)[i] = ue;
}

// ---------------------------------------------------------------------------
// K2c: G = F*A^T via MFMA f16 with split precision (round-9-proven math).
// Round-10: epilogue writes TWO regions matched to the hybrid consumer:
//   region A (rows rl&64==0, LDS-staged) / region B (rl&64, streamed),
//   addr(u32) = ((b*4+sl)*512 + (gj>>6)*64 + (rl&63))*32 + ((gj>>1)&31)
// Bijective over (gi, even gj); consumer reads word k as cols wv*64+2k,+1,
// rows s*128+l (A) / s*128+64+l (B) -- matches wq4 pairing.
// ---------------------------------------------------------------------------
__global__ __launch_bounds__(256, 4) void k_mfma_g(
    const _Float16* __restrict__ Fh, const _Float16* __restrict__ Fe,
    const _Float16* __restrict__ Ah, const _Float16* __restrict__ Ae,
    unsigned* __restrict__ GA, unsigned* __restrict__ GB) {
  int b = blockIdx.y;
  int bx = blockIdx.x;  // 64: ti = bx>>2 (16 row tiles), cj = bx&3
  int t = threadIdx.x, l = t & 63, wv = t >> 6;
  int i0 = (bx >> 2) * 32;
  int j0 = (bx & 3) * 128 + wv * 32;
  const _Float16* Fhb = Fh + (size_t)b * 131072;
  const _Float16* Feb = Fe + (size_t)b * 131072;
  const _Float16* Ahb = Ah + (size_t)b * 131072;
  const _Float16* Aeb = Ae + (size_t)b * 131072;

  int lr = l & 15, lk = (l >> 4) * 8;
  f32x4 acc00 = {0,0,0,0}, acc01 = {0,0,0,0}, acc10 = {0,0,0,0}, acc11 = {0,0,0,0};
  f32x4 ar00 = {0,0,0,0}, ar01 = {0,0,0,0}, ar10 = {0,0,0,0}, ar11 = {0,0,0,0};

  for (int kk = 0; kk < 256; kk += 32) {
    f16x8 af0 = *(const f16x8*)&Fhb[(size_t)(i0 + lr) * 256 + kk + lk];
    f16x8 af1 = *(const f16x8*)&Fhb[(size_t)(i0 + 16 + lr) * 256 + kk + lk];
    f16x8 ae0 = *(const f16x8*)&Feb[(size_t)(i0 + lr) * 256 + kk + lk];
    f16x8 ae1 = *(const f16x8*)&Feb[(size_t)(i0 + 16 + lr) * 256 + kk + lk];
    f16x8 bf0 = *(const f16x8*)&Ahb[(size_t)(j0 + lr) * 256 + kk + lk];
    f16x8 bf1 = *(const f16x8*)&Ahb[(size_t)(j0 + 16 + lr) * 256 + kk + lk];
    f16x8 be0 = *(const f16x8*)&Aeb[(size_t)(j0 + lr) * 256 + kk + lk];
    f16x8 be1 = *(const f16x8*)&Aeb[(size_t)(j0 + 16 + lr) * 256 + kk + lk];
    acc00 = __builtin_amdgcn_mfma_f32_16x16x32_f16(af0, bf0, acc00, 0, 0, 0);
    acc01 = __builtin_amdgcn_mfma_f32_16x16x32_f16(af0, bf1, acc01, 0, 0, 0);
    acc10 = __builtin_amdgcn_mfma_f32_16x16x32_f16(af1, bf0, acc10, 0, 0, 0);
    acc11 = __builtin_amdgcn_mfma_f32_16x16x32_f16(af1, bf1, acc11, 0, 0, 0);
    ar00 = __builtin_amdgcn_mfma_f32_16x16x32_f16(af0, be0, ar00, 0, 0, 0);
    ar01 = __builtin_amdgcn_mfma_f32_16x16x32_f16(af0, be1, ar01, 0, 0, 0);
    ar10 = __builtin_amdgcn_mfma_f32_16x16x32_f16(af1, be0, ar10, 0, 0, 0);
    ar11 = __builtin_amdgcn_mfma_f32_16x16x32_f16(af1, be1, ar11, 0, 0, 0);
    ar00 = __builtin_amdgcn_mfma_f32_16x16x32_f16(ae0, bf0, ar00, 0, 0, 0);
    ar01 = __builtin_amdgcn_mfma_f32_16x16x32_f16(ae0, bf1, ar01, 0, 0, 0);
    ar10 = __builtin_amdgcn_mfma_f32_16x16x32_f16(ae1, bf0, ar10, 0, 0, 0);
    ar11 = __builtin_amdgcn_mfma_f32_16x16x32_f16(ae1, bf1, ar11, 0, 0, 0);
  }

#pragma unroll
  for (int tr = 0; tr < 2; ++tr)
#pragma unroll
    for (int tc = 0; tc < 2; ++tc) {
      const f32x4* am = (tr == 0) ? ((tc == 0) ? &acc00 : &acc01)
                                  : ((tc == 0) ? &acc10 : &acc11);
      const f32x4* ae = (tr == 0) ? ((tc == 0) ? &ar00 : &ar01)
                                  : ((tc == 0) ? &ar10 : &ar11);
#pragma unroll
      for (int r = 0; r < 4; ++r) {
        float v = (*am)[r] + (*ae)[r] * (1.0f / 256.0f);
        float vp = __shfl_xor(v, 1);
        int gi = i0 + tr * 16 + (l >> 4) * 4 + r;
        int gj = j0 + tc * 16 + lr;
        if (!(l & 1)) {
          __half2 hh = __floats2half2_rn(v, vp);
          int sl = gi >> 7, rl = gi & 127;
          size_t idx =
              ((size_t)((b * 4 + sl) * 512 + (gj >> 6) * 64 + (rl & 63))) * 32 +
              ((gj >> 1) & 31);
          if (rl & 64) GB[idx] = *(unsigned*)&hh;
          else         GA[idx] = *(unsigned*)&hh;
        }
      }
    }
}

// ---------------------------------------------------------------------------
// K3: BLOCKED Gauss-Jordan inversion, NB=8 (SPD, no pivoting).
// ---------------------------------------------------------------------------
__global__ __launch_bounds__(512, 2) void k_invert(const float* __restrict__ Mk,
                                                   float* __restrict__ Mi) {
  int b = blockIdx.x;
  const float* src = Mk + (size_t)b * 65536;
  float* dst = Mi + (size_t)b * 65536;
  int t = threadIdx.x;
  int c = t & 255, rh = t >> 8;

  float a[128];
#pragma unroll
  for (int j = 0; j < 128; ++j) a[j] = src[(size_t)(rh * 128 + j) * 256 + c];

  __shared__ float colPan[256][8];
  __shared__ float rowPan[2][8][260];
  __shared__ float PiSh[64];
  __shared__ float Rp[8][260];

  int rh_s = __builtin_amdgcn_readfirstlane(rh);
  int cw_s = __builtin_amdgcn_readfirstlane((t >> 6) & 3);

  if (rh == 0) {
#pragma unroll
    for (int j = 0; j < 8; ++j) rowPan[0][j][c] = a[j];
  }
  __syncthreads();

  for (int s = 0; s < 32; ++s) {
    int kb = s * 8;
    int cur = s & 1, nxt = cur ^ 1;
    int kh = kb >> 7, kj = kb & 127;
    int khn = (kb + 8) >> 7, kjn = (kb + 8) & 127;
    bool mycol = (c >= kb) && (c < kb + 8);

    if (cw_s == (kb >> 6)) {
      if (mycol) {
        int f = c - kb;
#pragma unroll
        for (int j = 0; j < 128; ++j) colPan[rh * 128 + j][f] = a[j];
      }
    }
    if (t < 64) {
      int e = t >> 3, f = t & 7;
      float p = rowPan[cur][e][kb + f];
#pragma unroll
      for (int k2 = 0; k2 < 8; ++k2) {
        float piv = __shfl(p, k2 * 8 + k2);
        float rv = __shfl(p, k2 * 8 + f);
        float cv = __shfl(p, e * 8 + k2);
        float pivinv = 1.0f / piv;
        float srv = rv * pivinv;
        float gen = p - cv * srv;
        p = gen;
        if (e == k2) p = srv;
        if (f == k2) p = -cv * pivinv;
        if (e == k2 && f == k2) p = pivinv;
      }
      PiSh[t] = p;
    }
    __syncthreads();

    float rpan[8];
#pragma unroll
    for (int f2 = 0; f2 < 8; ++f2) rpan[f2] = rowPan[cur][f2][c];
    float rp[8];
#pragma unroll
    for (int e = 0; e < 8; ++e) {
      float4 p0 = *(const float4*)&PiSh[e * 8];
      float4 p1 = *(const float4*)&PiSh[e * 8 + 4];
      rp[e] = p0.x * rpan[0] + p0.y * rpan[1] + p0.z * rpan[2] + p0.w * rpan[3] +
              p1.x * rpan[4] + p1.y * rpan[5] + p1.z * rpan[6] + p1.w * rpan[7];
    }
    if (cw_s == (kb >> 6)) {
      if (mycol) {
        int f = c - kb;
#pragma unroll
        for (int e = 0; e < 8; ++e) rp[e] = PiSh[e * 8 + f];
      }
    }
#pragma unroll
    for (int e = 0; e < 8; ++e) Rp[e][c] = rp[e];

    bool myhalfk = (rh_s == kh);
    bool stashw = (s != 31) && (rh_s == khn);
#pragma unroll
    for (int j = 0; j < 128; ++j) {
      float4 c0 = *(const float4*)&colPan[rh * 128 + j][0];
      float4 c1 = *(const float4*)&colPan[rh * 128 + j][4];
      float aold = a[j];
      float nv = aold -
                 (c0.x * rp[0] + c0.y * rp[1] + c0.z * rp[2] + c0.w * rp[3] +
                  c1.x * rp[4] + c1.y * rp[5] + c1.z * rp[6] + c1.w * rp[7]);
      if (mycol) nv -= aold;
      if (myhalfk && j >= kj && j < kj + 8)
        nv = Rp[j - kj][c];
      a[j] = nv;
      if (stashw && j >= kjn && j < kjn + 8)
        rowPan[nxt][j - kjn][c] = nv;
    }
    __syncthreads();
  }

#pragma unroll
  for (int j = 0; j < 128; ++j) dst[(size_t)(rh * 128 + j) * 256 + c] = a[j];
}

// ---------------------------------------------------------------------------
// K4a: h = Minv * q
// ---------------------------------------------------------------------------
__global__ __launch_bounds__(256) void k_matvec_h(const float* __restrict__ Mi,
                                                  const float* __restrict__ q,
                                                  float* __restrict__ h) {
  int b = blockIdx.x, t = threadIdx.x;
  __shared__ float qs[256];
  qs[t] = q[(size_t)b * 256 + t];
  __syncthreads();
  const float* Mb = Mi + (size_t)b * 65536;
  float acc = 0.0f;
  for (int k = 0; k < 256; ++k) acc += Mb[(size_t)k * 256 + t] * qs[k];
  h[(size_t)b * 256 + t] = acc;
}

// K4b: d = A * h  via At columns
__global__ __launch_bounds__(512) void k_matvec_d(const float* __restrict__ At,
                                                  const float* __restrict__ h,
                                                  float* __restrict__ d) {
  int b = blockIdx.x, t = threadIdx.x;
  __shared__ float hs[256];
  if (t < 256) hs[t] = h[(size_t)b * 256 + t];
  __syncthreads();
  const float* Ab = At + (size_t)b * 131072;
  float acc = 0.0f;
  for (int n = 0; n < 256; ++n) acc += Ab[(size_t)n * 512 + t] * hs[n];
  d[(size_t)b * 512 + t] = acc;
}

// ---------------------------------------------------------------------------
// K6: ADMM loop — round-16: HYBRID G. Round-7 structure (706 us, proven),
// but per-iter G traffic split across two pipes:
//  - row-l half (region A): staged ONCE into LDS at kernel start, in a
//    b128 layout (GsV[(wv*8+j4)*64+l] -> lane-contiguous 1024 B reads,
//    conflict-free, 8 x ds_read_b128 per thread per iter). Same-thread
//    write->read needs no barrier.
//  - row-(64+l) half (region B): streamed per iter as 8 x dwordx4
//    (thread-major producer layout, 128 B contiguous per thread).
// Per-CU L2 bytes halve: 131 KB -> 65 KB/iter (~1170 cy share); the LDS
// phase (~600 cy) rides on the independent LDS pipe. Poll/exchange/update
// byte-identical to rounds 1-9.
// VALIDATION: LDS_Block_Size ~71KB; admm FETCH_SIZE drops vs round 9.
// ---------------------------------------------------------------------------
__global__ __launch_bounds__(512) void k_admm4(
    const unsigned* __restrict__ GA, const unsigned* __restrict__ GB,
    const float* __restrict__ dvec, const float* __restrict__ lv,
    const float* __restrict__ uv, unsigned long long* __restrict__ wtag,
    float* __restrict__ Sbuf) {
  int g = blockIdx.x;
  int b = (g & 7) + 8 * ((g >> 3) & 7);
  int s = g >> 6;
  int t = threadIdx.x;
  int l = t & 63, wv = t >> 6;
  int c0 = wv * 64;

  __shared__ __align__(16) unsigned Gs[16384];   // 64 KB staged row-l G
  __shared__ __align__(16) float wbuf[8][64];
  __shared__ float part[2][8][128];

  const uint4* gA =
      (const uint4*)(GA + ((size_t)(b * 4 + s) * 512 + c0 + l) * 32);
  const uint4* gB =
      (const uint4*)(GB + ((size_t)(b * 4 + s) * 512 + c0 + l) * 32);
  uint4* GsV = (uint4*)Gs;

#pragma unroll
  for (int j4 = 0; j4 < 8; ++j4)
    GsV[(wv * 8 + j4) * 64 + l] = gA[j4];  // same-thread readback, no barrier

  float zreg = 0.0f, yreg = 0.0f, Sreg = 0.0f;
  float lreg = 0.0f, ureg = 0.0f, dreg = 0.0f;
  if (t < 128) {
    lreg = lv[(size_t)b * 512 + s * 128 + t];
    ureg = uv[(size_t)b * 512 + s * 128 + t];
    dreg = dvec[(size_t)b * 512 + s * 128 + t];
  }
  wbuf[wv][l] = 0.0f;  // w_0 = 0

  unsigned long long* wt0 = wtag + (size_t)b * 512;
  unsigned long long* wt1 = wtag + 32768 + (size_t)b * 512;
  const float4* wq4 = (const float4*)(wbuf[wv]);

  for (int it = 0; it < NITERS; ++it) {
    // Region-B loads for this iteration (8 x dwordx4, 128 B contiguous).
    uint4 gb[8];
#pragma unroll
    for (int k = 0; k < 8; ++k) gb[k] = gB[k];

    if (it > 0) {
      unsigned long long* wp = (it & 1) ? wt1 : wt0;
      unsigned want = (unsigned)it;
      unsigned long long v = __hip_atomic_load(&wp[c0 + l], __ATOMIC_RELAXED,
                                               __HIP_MEMORY_SCOPE_AGENT);
      bool got = ((unsigned)(v >> 32) == want);
      while (!__all(got)) {
        if (!got) {
          unsigned long long v2 = __hip_atomic_load(
              &wp[c0 + l], __ATOMIC_RELAXED, __HIP_MEMORY_SCOPE_AGENT);
          if ((unsigned)(v2 >> 32) == want) { v = v2; got = true; }
        }
      }
      wbuf[wv][l] = __uint_as_float((unsigned)(v & 0xffffffffu));
    }

    float r0a = 0.f, r0b = 0.f, r1a = 0.f, r1b = 0.f;
#pragma unroll
    for (int j = 0; j < 8; ++j) {
      float4 wa = wq4[2 * j];
      float4 wc = wq4[2 * j + 1];
      uint4 ga = GsV[(wv * 8 + j) * 64 + l];   // ds_read_b128, conflict-free
      uint4 gv = gb[j];
      float2 fa0 = __half22float2(*(__half2*)&ga.x);
      float2 fa1 = __half22float2(*(__half2*)&ga.y);
      float2 fa2 = __half22float2(*(__half2*)&ga.z);
      float2 fa3 = __half22float2(*(__half2*)&ga.w);
      float2 fb0 = __half22float2(*(__half2*)&gv.x);
      float2 fb1 = __half22float2(*(__half2*)&gv.y);
      float2 fb2 = __half22float2(*(__half2*)&gv.z);
      float2 fb3 = __half22float2(*(__half2*)&gv.w);
      r0a += fa0.x * wa.x + fa0.y * wa.y + fa1.x * wa.z + fa1.y * wa.w;
      r0b += fa2.x * wc.x + fa2.y * wc.y + fa3.x * wc.z + fa3.y * wc.w;
      r1a += fb0.x * wa.x + fb0.y * wa.y + fb1.x * wa.z + fb1.y * wa.w;
      r1b += fb2.x * wc.x + fb2.y * wc.y + fb3.x * wc.z + fb3.y * wc.w;
    }
    int pp = it & 1;
    part[pp][wv][l] = r0a + r0b;
    part[pp][wv][64 + l] = r1a + r1b;
    __syncthreads();  // the ONLY barrier

    if (t < 128) {
      float w_old = RHO_C * zreg - yreg;
      Sreg = w_old - 0.6f * Sreg;
      float p = part[pp][0][t] + part[pp][1][t] + part[pp][2][t] +
                part[pp][3][t] + part[pp][4][t] + part[pp][5][t] +
                part[pp][6][t] + part[pp][7][t];
      float zt = p - dreg;
      float zh = ALPHA_C * zt + (1.0f - ALPHA_C) * zreg;
      float zc = zh + yreg * (1.0f / RHO_C);
      zc = fminf(fmaxf(zc, lreg), ureg);
      yreg += RHO_C * (zh - zc);
      zreg = zc;
      if (it < NITERS - 1) {
        float wn = RHO_C * zreg - yreg;
        unsigned long long pk =
            ((unsigned long long)(unsigned)(it + 1) << 32) |
            (unsigned long long)__float_as_uint(wn);
        unsigned long long* wp = ((it + 1) & 1) ? wt1 : wt0;
        __hip_atomic_store(&wp[s * 128 + t], pk, __ATOMIC_RELAXED,
                           __HIP_MEMORY_SCOPE_AGENT);
      }
    }
  }

  if (t < 128) Sbuf[(size_t)b * 512 + s * 128 + t] = Sreg;
}

// ---------------------------------------------------------------------------
// K7: epilogue  x = Minv * (alpha * A^T S - q)
// ---------------------------------------------------------------------------
__global__ __launch_bounds__(256) void k_final(
    const float* __restrict__ A, const float* __restrict__ q,
    const float* __restrict__ Mi, const float* __restrict__ Sbuf,
    float* __restrict__ xout) {
  int b = blockIdx.x, t = threadIdx.x;
  __shared__ float Ssh[512];
  __shared__ float uu[256];
  for (int i = t; i < 512; i += 256) Ssh[i] = Sbuf[(size_t)b * 512 + i];
  __syncthreads();
  const float* Ab = A + (size_t)b * 131072;
  float acc = 0.0f;
  for (int m = 0; m < 512; ++m) acc += Ab[(size_t)m * 256 + t] * Ssh[m];
  uu[t] = ALPHA_C * acc - q[(size_t)b * 256 + t];
  __syncthreads();
  const float* Mb = Mi + (size_t)b * 65536;
  float x = 0.0f;
  for (int kk = 0; kk < 256; ++kk) x += Mb[(size_t)kk * 256 + t] * uu[kk];
  xout[(size_t)b * 256 + t] = x;
}

// ---------------------------------------------------------------------------
// Workspace layout (float-slot offsets):
//   At: [0, 8388608)            transpose; dead after k_matvec_d
//   Ah: [0, 4194304)  Ae: [4194304, 8388608)   (written after matvec_d)
//   Mi: [8388608, 12582912)     live to the end
//   Mk: [12582912, 16777216)    dead after k_invert
//   GA: [12582912, 16777216)    region A (16 MB, overwrites dead Mk)
//   GB: [16777216, 20971520)    region B (16 MB)
//   Fh: [20971520, 25165824)  Fe: [25165824, 29360128)
//   hv/dv/Sbuf: [29360128, 29442048)
//   wtag: [29442048, 29573120)  zeroed by hipMemsetAsync each launch
// ---------------------------------------------------------------------------
extern "C" void kernel_launch(void* const* d_in, const int* in_sizes, int n_in,
                              void* d_out, int out_size, void* d_ws, size_t ws_size,
                              hipStream_t stream) {
  (void)in_sizes; (void)n_in; (void)out_size; (void)ws_size;
  const float* P = (const float*)d_in[0];
  const float* q = (const float*)d_in[1];
  const float* Av = (const float*)d_in[2];
  const float* lv = (const float*)d_in[3];
  const float* uv = (const float*)d_in[4];
  float* xout = (float*)d_out;

  float* ws = (float*)d_ws;
  float* At = ws;
  unsigned* Ah = (unsigned*)ws;
  unsigned* Ae = (unsigned*)(ws + 4194304);
  float* Mi = ws + 8388608;
  float* Mk = ws + 12582912;
  unsigned* GA = (unsigned*)(ws + 12582912);
  unsigned* GB = (unsigned*)(ws + 16777216);
  float* Fh = ws + 20971520;
  float* Fe = ws + 25165824;
  float* hv = ws + 29360128;
  float* dv = ws + 29376512;
  float* Sbuf = ws + 29409280;
  unsigned long long* wtag = (unsigned long long*)(ws + 29442048);

  hipMemsetAsync(wtag, 0, 131072 * 4, stream);  // scrub stale tags (512 KB)

  k_transpose<<<dim3(8, 16, 64), dim3(32, 8), 0, stream>>>(Av, At);
  k_ntgemm<<<dim3(4, 64), 256, 0, stream>>>(At, At, Mk, nullptr, 256, 256, 512,
                                            131072LL, 131072LL, 65536LL,
                                            RHO_C, P, 2, 0);
  k_invert<<<64, 512, 0, stream>>>(Mk, Mi);
  k_matvec_h<<<64, 256, 0, stream>>>(Mi, q, hv);
  k_matvec_d<<<64, 512, 0, stream>>>(At, hv, dv);
  // At is now dead: overwrite its region with split-fp16 A
  k_cast_split<<<8192, 256, 0, stream>>>(Av, Ah, Ae, 2097152);
  // F = Av * Mi  (fp32 compute, split-fp16 output)
  k_ntgemm<<<dim3(8, 64), 256, 0, stream>>>(Av, Mi, Fh, Fe, 512, 256, 256,
                                            131072LL, 65536LL, 0LL,
                                            1.0f, nullptr, 2, 2);
  // G = F * A^T  via MFMA, two-region hybrid output
  k_mfma_g<<<dim3(64, 64), 256, 0, stream>>>(
      (const _Float16*)Fh, (const _Float16*)Fe,
      (const _Float16*)Ah, (const _Float16*)Ae, GA, GB);
  k_admm4<<<256, 512, 0, stream>>>(GA, GB, dv, lv, uv, wtag, Sbuf);
  k_final<<<64, 256, 0, stream>>>(Av, q, Mi, Sbuf, xout);
}

// Round 11
// 1556.677 us; speedup vs baseline: 1.0541x; 1.0541x over previous
//
#include <hip/hip_runtime.h>
#include <hip/hip_fp16.h>

#define N_VAR 256
#define M_CON 512
#define BATCH 64
#define SIGMA_C 1e-6f
#define RHO_C 0.1f
#define ALPHA_C 1.6f
#define NITERS 500

typedef _Float16 f16x8 __attribute__((ext_vector_type(8)));
typedef float f32x4 __attribute__((ext_vector_type(4)));

// ---------------------------------------------------------------------------
// K1: transpose A [512][256] -> At [256][512] per batch
// ---------------------------------------------------------------------------
__global__ __launch_bounds__(256) void k_transpose(const float* __restrict__ A,
                                                   float* __restrict__ At) {
  __shared__ float tile[32][33];
  int b = blockIdx.z;
  int n0 = blockIdx.x * 32;
  int m0 = blockIdx.y * 32;
  const float* Ab = A + (size_t)b * (M_CON * N_VAR);
  float* Atb = At + (size_t)b * (M_CON * N_VAR);
  int tx = threadIdx.x, ty = threadIdx.y;  // (32, 8)
#pragma unroll
  for (int j = 0; j < 32; j += 8)
    tile[ty + j][tx] = Ab[(size_t)(m0 + ty + j) * N_VAR + n0 + tx];
  __syncthreads();
#pragma unroll
  for (int j = 0; j < 32; j += 8)
    Atb[(size_t)(n0 + ty + j) * M_CON + m0 + tx] = tile[tx][ty + j];
}

// ---------------------------------------------------------------------------
// K2b: split-fp16 cast: oh = half(v), oe = half((v - float(oh)) * 256)
// ---------------------------------------------------------------------------
__global__ __launch_bounds__(256) void k_cast_split(
    const float* __restrict__ in, unsigned* __restrict__ oh,
    unsigned* __restrict__ oe, int n4) {
  int i = blockIdx.x * 256 + threadIdx.x;
  if (i >= n4) return;
  float4 v = ((const float4*)in)[i];
  __half2 h01 = __floats2half2_rn(v.x, v.y);
  __half2 h23 = __floats2half2_rn(v.z, v.w);
  float2 f01 = __half22float2(h01);
  float2 f23 = __half22float2(h23);
  __half2 e01 = __floats2half2_rn((v.x - f01.x) * 256.0f, (v.y - f01.y) * 256.0f);
  __half2 e23 = __floats2half2_rn((v.z - f23.x) * 256.0f, (v.w - f23.y) * 256.0f);
  uint2 uh; uh.x = *(unsigned*)&h01; uh.y = *(unsigned*)&h23;
  uint2 ue; ue.x = *(unsigned*)&e01; ue.y = *(unsigned*)&e23;
  ((uint2*)oh)[i] = uh;
  ((uint2*)oe)[i] = ue;
}

// ---------------------------------------------------------------------------
// K2n: generic split-fp16 NT MFMA GEMM: C[i][j] = sum_k X[i][k]*Y[j][k],
// X = Xh + Xe/256, Y = Yh + Ye/256 (all fp16): 4 products with fp32 accum
// -> rel error ~2^-22 (fp32-class; safe for Mk -> inversion).
// Fragment layout mirrors round-9-PROVEN k_mfma_g exactly.
// mode 0: C0 = fp32, + alpha, + diag(diagv+SIGMA) on gi==gj (row stride 256)
// mode 1: C0/C1 = split-fp16 halves (row stride 256)
// ---------------------------------------------------------------------------
__global__ __launch_bounds__(256, 4) void k_mfma_nt(
    const _Float16* __restrict__ Xh, const _Float16* __restrict__ Xe,
    const _Float16* __restrict__ Yh, const _Float16* __restrict__ Ye,
    float* __restrict__ C0, float* __restrict__ C1,
    int K, int jTiles, long long bsX, long long bsY, long long bsC,
    float alpha, const float* __restrict__ diagv, int mode) {
  int b = blockIdx.y;
  int bx = blockIdx.x;
  int t = threadIdx.x, l = t & 63, wv = t >> 6;
  int i0 = (bx / jTiles) * 32;
  int j0 = (bx % jTiles) * 128 + wv * 32;
  const _Float16* Xhb = Xh + (size_t)b * bsX;
  const _Float16* Xeb = Xe + (size_t)b * bsX;
  const _Float16* Yhb = Yh + (size_t)b * bsY;
  const _Float16* Yeb = Ye + (size_t)b * bsY;

  int lr = l & 15, lk = (l >> 4) * 8;
  f32x4 m00 = {0,0,0,0}, m01 = {0,0,0,0}, m10 = {0,0,0,0}, m11 = {0,0,0,0};
  f32x4 c00 = {0,0,0,0}, c01 = {0,0,0,0}, c10 = {0,0,0,0}, c11 = {0,0,0,0};
  f32x4 s00 = {0,0,0,0}, s01 = {0,0,0,0}, s10 = {0,0,0,0}, s11 = {0,0,0,0};

  for (int kk = 0; kk < K; kk += 32) {
    f16x8 xh0 = *(const f16x8*)&Xhb[(size_t)(i0 + lr) * K + kk + lk];
    f16x8 xh1 = *(const f16x8*)&Xhb[(size_t)(i0 + 16 + lr) * K + kk + lk];
    f16x8 xe0 = *(const f16x8*)&Xeb[(size_t)(i0 + lr) * K + kk + lk];
    f16x8 xe1 = *(const f16x8*)&Xeb[(size_t)(i0 + 16 + lr) * K + kk + lk];
    f16x8 yh0 = *(const f16x8*)&Yhb[(size_t)(j0 + lr) * K + kk + lk];
    f16x8 yh1 = *(const f16x8*)&Yhb[(size_t)(j0 + 16 + lr) * K + kk + lk];
    f16x8 ye0 = *(const f16x8*)&Yeb[(size_t)(j0 + lr) * K + kk + lk];
    f16x8 ye1 = *(const f16x8*)&Yeb[(size_t)(j0 + 16 + lr) * K + kk + lk];
    m00 = __builtin_amdgcn_mfma_f32_16x16x32_f16(xh0, yh0, m00, 0, 0, 0);
    m01 = __builtin_amdgcn_mfma_f32_16x16x32_f16(xh0, yh1, m01, 0, 0, 0);
    m10 = __builtin_amdgcn_mfma_f32_16x16x32_f16(xh1, yh0, m10, 0, 0, 0);
    m11 = __builtin_amdgcn_mfma_f32_16x16x32_f16(xh1, yh1, m11, 0, 0, 0);
    c00 = __builtin_amdgcn_mfma_f32_16x16x32_f16(xh0, ye0, c00, 0, 0, 0);
    c01 = __builtin_amdgcn_mfma_f32_16x16x32_f16(xh0, ye1, c01, 0, 0, 0);
    c10 = __builtin_amdgcn_mfma_f32_16x16x32_f16(xh1, ye0, c10, 0, 0, 0);
    c11 = __builtin_amdgcn_mfma_f32_16x16x32_f16(xh1, ye1, c11, 0, 0, 0);
    c00 = __builtin_amdgcn_mfma_f32_16x16x32_f16(xe0, yh0, c00, 0, 0, 0);
    c01 = __builtin_amdgcn_mfma_f32_16x16x32_f16(xe0, yh1, c01, 0, 0, 0);
    c10 = __builtin_amdgcn_mfma_f32_16x16x32_f16(xe1, yh0, c10, 0, 0, 0);
    c11 = __builtin_amdgcn_mfma_f32_16x16x32_f16(xe1, yh1, c11, 0, 0, 0);
    s00 = __builtin_amdgcn_mfma_f32_16x16x32_f16(xe0, ye0, s00, 0, 0, 0);
    s01 = __builtin_amdgcn_mfma_f32_16x16x32_f16(xe0, ye1, s01, 0, 0, 0);
    s10 = __builtin_amdgcn_mfma_f32_16x16x32_f16(xe1, ye0, s10, 0, 0, 0);
    s11 = __builtin_amdgcn_mfma_f32_16x16x32_f16(xe1, ye1, s11, 0, 0, 0);
  }

#pragma unroll
  for (int tr = 0; tr < 2; ++tr)
#pragma unroll
    for (int tc = 0; tc < 2; ++tc) {
      f32x4 vm = tr ? (tc ? m11 : m10) : (tc ? m01 : m00);
      f32x4 vc = tr ? (tc ? c11 : c10) : (tc ? c01 : c00);
      f32x4 vs = tr ? (tc ? s11 : s10) : (tc ? s01 : s00);
#pragma unroll
      for (int r = 0; r < 4; ++r) {
        float v = (vm[r] + vc[r] * (1.0f / 256.0f) +
                   vs[r] * (1.0f / 65536.0f)) * alpha;
        int gi = i0 + tr * 16 + (l >> 4) * 4 + r;
        int gj = j0 + tc * 16 + lr;
        if (mode == 0) {
          if (diagv != nullptr && gi == gj)
            v += diagv[(size_t)b * N_VAR + gi] + SIGMA_C;
          C0[(size_t)b * bsC + (size_t)gi * 256 + gj] = v;
        } else {
          _Float16 fh = (_Float16)v;
          _Float16 fe = (_Float16)((v - (float)fh) * 256.0f);
          ((_Float16*)C0)[(size_t)b * bsC + (size_t)gi * 256 + gj] = fh;
          ((_Float16*)C1)[(size_t)b * bsC + (size_t)gi * 256 + gj] = fe;
        }
      }
    }
}

// ---------------------------------------------------------------------------
// K2c: G = F*A^T via MFMA f16, split precision, packed ADMM output.
// ROUND-9 PROVEN (absmax 0.043). Unchanged.
// ---------------------------------------------------------------------------
__global__ __launch_bounds__(256, 4) void k_mfma_g(
    const _Float16* __restrict__ Fh, const _Float16* __restrict__ Fe,
    const _Float16* __restrict__ Ah, const _Float16* __restrict__ Ae,
    unsigned* __restrict__ Gp) {
  int b = blockIdx.y;
  int bx = blockIdx.x;
  int t = threadIdx.x, l = t & 63, wv = t >> 6;
  int i0 = (bx >> 2) * 32;
  int j0 = (bx & 3) * 128 + wv * 32;
  const _Float16* Fhb = Fh + (size_t)b * 131072;
  const _Float16* Feb = Fe + (size_t)b * 131072;
  const _Float16* Ahb = Ah + (size_t)b * 131072;
  const _Float16* Aeb = Ae + (size_t)b * 131072;
  unsigned* Gpb = Gp + (size_t)b * 131072;

  int lr = l & 15, lk = (l >> 4) * 8;
  f32x4 acc00 = {0,0,0,0}, acc01 = {0,0,0,0}, acc10 = {0,0,0,0}, acc11 = {0,0,0,0};
  f32x4 ar00 = {0,0,0,0}, ar01 = {0,0,0,0}, ar10 = {0,0,0,0}, ar11 = {0,0,0,0};

  for (int kk = 0; kk < 256; kk += 32) {
    f16x8 af0 = *(const f16x8*)&Fhb[(size_t)(i0 + lr) * 256 + kk + lk];
    f16x8 af1 = *(const f16x8*)&Fhb[(size_t)(i0 + 16 + lr) * 256 + kk + lk];
    f16x8 ae0 = *(const f16x8*)&Feb[(size_t)(i0 + lr) * 256 + kk + lk];
    f16x8 ae1 = *(const f16x8*)&Feb[(size_t)(i0 + 16 + lr) * 256 + kk + lk];
    f16x8 bf0 = *(const f16x8*)&Ahb[(size_t)(j0 + lr) * 256 + kk + lk];
    f16x8 bf1 = *(const f16x8*)&Ahb[(size_t)(j0 + 16 + lr) * 256 + kk + lk];
    f16x8 be0 = *(const f16x8*)&Aeb[(size_t)(j0 + lr) * 256 + kk + lk];
    f16x8 be1 = *(const f16x8*)&Aeb[(size_t)(j0 + 16 + lr) * 256 + kk + lk];
    acc00 = __builtin_amdgcn_mfma_f32_16x16x32_f16(af0, bf0, acc00, 0, 0, 0);
    acc01 = __builtin_amdgcn_mfma_f32_16x16x32_f16(af0, bf1, acc01, 0, 0, 0);
    acc10 = __builtin_amdgcn_mfma_f32_16x16x32_f16(af1, bf0, acc10, 0, 0, 0);
    acc11 = __builtin_amdgcn_mfma_f32_16x16x32_f16(af1, bf1, acc11, 0, 0, 0);
    ar00 = __builtin_amdgcn_mfma_f32_16x16x32_f16(af0, be0, ar00, 0, 0, 0);
    ar01 = __builtin_amdgcn_mfma_f32_16x16x32_f16(af0, be1, ar01, 0, 0, 0);
    ar10 = __builtin_amdgcn_mfma_f32_16x16x32_f16(af1, be0, ar10, 0, 0, 0);
    ar11 = __builtin_amdgcn_mfma_f32_16x16x32_f16(af1, be1, ar11, 0, 0, 0);
    ar00 = __builtin_amdgcn_mfma_f32_16x16x32_f16(ae0, bf0, ar00, 0, 0, 0);
    ar01 = __builtin_amdgcn_mfma_f32_16x16x32_f16(ae0, bf1, ar01, 0, 0, 0);
    ar10 = __builtin_amdgcn_mfma_f32_16x16x32_f16(ae1, bf0, ar10, 0, 0, 0);
    ar11 = __builtin_amdgcn_mfma_f32_16x16x32_f16(ae1, bf1, ar11, 0, 0, 0);
  }

#pragma unroll
  for (int tr = 0; tr < 2; ++tr)
#pragma unroll
    for (int tc = 0; tc < 2; ++tc) {
      const f32x4* am = (tr == 0) ? ((tc == 0) ? &acc00 : &acc01)
                                  : ((tc == 0) ? &acc10 : &acc11);
      const f32x4* ae = (tr == 0) ? ((tc == 0) ? &ar00 : &ar01)
                                  : ((tc == 0) ? &ar10 : &ar11);
#pragma unroll
      for (int r = 0; r < 4; ++r) {
        float v = (*am)[r] + (*ae)[r] * (1.0f / 256.0f);
        float vp = __shfl_xor(v, 1);
        int gi = i0 + tr * 16 + (l >> 4) * 4 + r;
        int gj = j0 + tc * 16 + lr;
        if (!(l & 1)) {
          __half2 hh = __floats2half2_rn(v, vp);
          int sl = gi >> 7, rl = gi & 127;
          int t2 = ((((gj >> 7) << 1) | (rl >> 6)) << 6) | (rl & 63);
          Gpb[(size_t)sl * 32768 + ((gj & 127) >> 1) * 512 + t2] = *(unsigned*)&hh;
        }
      }
    }
}

// ---------------------------------------------------------------------------
// K3: BLOCKED Gauss-Jordan inversion, NB=8 (SPD, no pivoting).
// ---------------------------------------------------------------------------
__global__ __launch_bounds__(512, 2) void k_invert(const float* __restrict__ Mk,
                                                   float* __restrict__ Mi) {
  int b = blockIdx.x;
  const float* src = Mk + (size_t)b * 65536;
  float* dst = Mi + (size_t)b * 65536;
  int t = threadIdx.x;
  int c = t & 255, rh = t >> 8;

  float a[128];
#pragma unroll
  for (int j = 0; j < 128; ++j) a[j] = src[(size_t)(rh * 128 + j) * 256 + c];

  __shared__ float colPan[256][8];
  __shared__ float rowPan[2][8][260];
  __shared__ float PiSh[64];
  __shared__ float Rp[8][260];

  int rh_s = __builtin_amdgcn_readfirstlane(rh);
  int cw_s = __builtin_amdgcn_readfirstlane((t >> 6) & 3);

  if (rh == 0) {
#pragma unroll
    for (int j = 0; j < 8; ++j) rowPan[0][j][c] = a[j];
  }
  __syncthreads();

  for (int s = 0; s < 32; ++s) {
    int kb = s * 8;
    int cur = s & 1, nxt = cur ^ 1;
    int kh = kb >> 7, kj = kb & 127;
    int khn = (kb + 8) >> 7, kjn = (kb + 8) & 127;
    bool mycol = (c >= kb) && (c < kb + 8);

    if (cw_s == (kb >> 6)) {
      if (mycol) {
        int f = c - kb;
#pragma unroll
        for (int j = 0; j < 128; ++j) colPan[rh * 128 + j][f] = a[j];
      }
    }
    if (t < 64) {
      int e = t >> 3, f = t & 7;
      float p = rowPan[cur][e][kb + f];
#pragma unroll
      for (int k2 = 0; k2 < 8; ++k2) {
        float piv = __shfl(p, k2 * 8 + k2);
        float rv = __shfl(p, k2 * 8 + f);
        float cv = __shfl(p, e * 8 + k2);
        float pivinv = 1.0f / piv;
        float srv = rv * pivinv;
        float gen = p - cv * srv;
        p = gen;
        if (e == k2) p = srv;
        if (f == k2) p = -cv * pivinv;
        if (e == k2 && f == k2) p = pivinv;
      }
      PiSh[t] = p;
    }
    __syncthreads();

    float rpan[8];
#pragma unroll
    for (int f2 = 0; f2 < 8; ++f2) rpan[f2] = rowPan[cur][f2][c];
    float rp[8];
#pragma unroll
    for (int e = 0; e < 8; ++e) {
      float4 p0 = *(const float4*)&PiSh[e * 8];
      float4 p1 = *(const float4*)&PiSh[e * 8 + 4];
      rp[e] = p0.x * rpan[0] + p0.y * rpan[1] + p0.z * rpan[2] + p0.w * rpan[3] +
              p1.x * rpan[4] + p1.y * rpan[5] + p1.z * rpan[6] + p1.w * rpan[7];
    }
    if (cw_s == (kb >> 6)) {
      if (mycol) {
        int f = c - kb;
#pragma unroll
        for (int e = 0; e < 8; ++e) rp[e] = PiSh[e * 8 + f];
      }
    }
#pragma unroll
    for (int e = 0; e < 8; ++e) Rp[e][c] = rp[e];

    bool myhalfk = (rh_s == kh);
    bool stashw = (s != 31) && (rh_s == khn);
#pragma unroll
    for (int j = 0; j < 128; ++j) {
      float4 c0 = *(const float4*)&colPan[rh * 128 + j][0];
      float4 c1 = *(const float4*)&colPan[rh * 128 + j][4];
      float aold = a[j];
      float nv = aold -
                 (c0.x * rp[0] + c0.y * rp[1] + c0.z * rp[2] + c0.w * rp[3] +
                  c1.x * rp[4] + c1.y * rp[5] + c1.z * rp[6] + c1.w * rp[7]);
      if (mycol) nv -= aold;
      if (myhalfk && j >= kj && j < kj + 8)
        nv = Rp[j - kj][c];
      a[j] = nv;
      if (stashw && j >= kjn && j < kjn + 8)
        rowPan[nxt][j - kjn][c] = nv;
    }
    __syncthreads();
  }

#pragma unroll
  for (int j = 0; j < 128; ++j) dst[(size_t)(rh * 128 + j) * 256 + c] = a[j];
}

// ---------------------------------------------------------------------------
// K4a: h = Minv * q
// ---------------------------------------------------------------------------
__global__ __launch_bounds__(256) void k_matvec_h(const float* __restrict__ Mi,
                                                  const float* __restrict__ q,
                                                  float* __restrict__ h) {
  int b = blockIdx.x, t = threadIdx.x;
  __shared__ float qs[256];
  qs[t] = q[(size_t)b * 256 + t];
  __syncthreads();
  const float* Mb = Mi + (size_t)b * 65536;
  float acc = 0.0f;
  for (int k = 0; k < 256; ++k) acc += Mb[(size_t)k * 256 + t] * qs[k];
  h[(size_t)b * 256 + t] = acc;
}

// K4b: d = A * h  via At columns
__global__ __launch_bounds__(512) void k_matvec_d(const float* __restrict__ At,
                                                  const float* __restrict__ h,
                                                  float* __restrict__ d) {
  int b = blockIdx.x, t = threadIdx.x;
  __shared__ float hs[256];
  if (t < 256) hs[t] = h[(size_t)b * 256 + t];
  __syncthreads();
  const float* Ab = At + (size_t)b * 131072;
  float acc = 0.0f;
  for (int n = 0; n < 256; ++n) acc += Ab[(size_t)n * 512 + t] * hs[n];
  d[(size_t)b * 512 + t] = acc;
}

// ---------------------------------------------------------------------------
// K6: ADMM loop — ROUND-7 EXACT (706 us, the measured floor of this exchange
// structure across 10 structural variants). Frozen.
// ---------------------------------------------------------------------------
__global__ __launch_bounds__(512) void k_admm4(
    const unsigned* __restrict__ Gpk_g, const float* __restrict__ dvec,
    const float* __restrict__ lv, const float* __restrict__ uv,
    unsigned long long* __restrict__ wtag, float* __restrict__ Sbuf) {
  int g = blockIdx.x;
  int b = (g & 7) + 8 * ((g >> 3) & 7);
  int s = g >> 6;
  int t = threadIdx.x;
  int l = t & 63, wv = t >> 6;
  int c0 = wv * 64;
  int cg = wv >> 1, hc = wv & 1;

  __shared__ __align__(16) float wbuf[8][64];
  __shared__ float part[2][8][128];

  const unsigned* gsrc =
      Gpk_g + (size_t)(b * 4 + s) * 32768 + (size_t)(hc * 32) * 512 + cg * 128 + l;

  float zreg = 0.0f, yreg = 0.0f, Sreg = 0.0f;
  float lreg = 0.0f, ureg = 0.0f, dreg = 0.0f;
  if (t < 128) {
    lreg = lv[(size_t)b * 512 + s * 128 + t];
    ureg = uv[(size_t)b * 512 + s * 128 + t];
    dreg = dvec[(size_t)b * 512 + s * 128 + t];
  }
  wbuf[wv][l] = 0.0f;  // w_0 = 0

  unsigned long long* wt0 = wtag + (size_t)b * 512;
  unsigned long long* wt1 = wtag + 32768 + (size_t)b * 512;
  const float4* wq4 = (const float4*)(wbuf[wv]);

  for (int it = 0; it < NITERS; ++it) {
    if (it > 0) {
      unsigned long long* wp = (it & 1) ? wt1 : wt0;
      unsigned want = (unsigned)it;
      unsigned long long v = __hip_atomic_load(&wp[c0 + l], __ATOMIC_RELAXED,
                                               __HIP_MEMORY_SCOPE_AGENT);
      bool got = ((unsigned)(v >> 32) == want);
      while (!__all(got)) {
        if (!got) {
          unsigned long long v2 = __hip_atomic_load(
              &wp[c0 + l], __ATOMIC_RELAXED, __HIP_MEMORY_SCOPE_AGENT);
          if ((unsigned)(v2 >> 32) == want) { v = v2; got = true; }
        }
      }
      wbuf[wv][l] = __uint_as_float((unsigned)(v & 0xffffffffu));
    }

    float r0a = 0.f, r0b = 0.f, r1a = 0.f, r1b = 0.f;
#pragma unroll
    for (int j = 0; j < 8; ++j) {
      float4 wa = wq4[2 * j];
      float4 wc = wq4[2 * j + 1];
      unsigned a0 = gsrc[(4 * j + 0) * 512];
      unsigned a1 = gsrc[(4 * j + 1) * 512];
      unsigned a2 = gsrc[(4 * j + 2) * 512];
      unsigned a3 = gsrc[(4 * j + 3) * 512];
      unsigned b0 = gsrc[(4 * j + 0) * 512 + 64];
      unsigned b1 = gsrc[(4 * j + 1) * 512 + 64];
      unsigned b2 = gsrc[(4 * j + 2) * 512 + 64];
      unsigned b3 = gsrc[(4 * j + 3) * 512 + 64];
      float2 fa0 = __half22float2(*(__half2*)&a0);
      float2 fa1 = __half22float2(*(__half2*)&a1);
      float2 fa2 = __half22float2(*(__half2*)&a2);
      float2 fa3 = __half22float2(*(__half2*)&a3);
      float2 fb0 = __half22float2(*(__half2*)&b0);
      float2 fb1 = __half22float2(*(__half2*)&b1);
      float2 fb2 = __half22float2(*(__half2*)&b2);
      float2 fb3 = __half22float2(*(__half2*)&b3);
      r0a += fa0.x * wa.x + fa0.y * wa.y + fa1.x * wa.z + fa1.y * wa.w;
      r0b += fa2.x * wc.x + fa2.y * wc.y + fa3.x * wc.z + fa3.y * wc.w;
      r1a += fb0.x * wa.x + fb0.y * wa.y + fb1.x * wa.z + fb1.y * wa.w;
      r1b += fb2.x * wc.x + fb2.y * wc.y + fb3.x * wc.z + fb3.y * wc.w;
    }
    int pp = it & 1;
    part[pp][wv][l] = r0a + r0b;
    part[pp][wv][64 + l] = r1a + r1b;
    __syncthreads();  // the ONLY barrier

    if (t < 128) {
      float w_old = RHO_C * zreg - yreg;
      Sreg = w_old - 0.6f * Sreg;
      float p = part[pp][0][t] + part[pp][1][t] + part[pp][2][t] +
                part[pp][3][t] + part[pp][4][t] + part[pp][5][t] +
                part[pp][6][t] + part[pp][7][t];
      float zt = p - dreg;
      float zh = ALPHA_C * zt + (1.0f - ALPHA_C) * zreg;
      float zc = zh + yreg * (1.0f / RHO_C);
      zc = fminf(fmaxf(zc, lreg), ureg);
      yreg += RHO_C * (zh - zc);
      zreg = zc;
      if (it < NITERS - 1) {
        float wn = RHO_C * zreg - yreg;
        unsigned long long pk =
            ((unsigned long long)(unsigned)(it + 1) << 32) |
            (unsigned long long)__float_as_uint(wn);
        unsigned long long* wp = ((it + 1) & 1) ? wt1 : wt0;
        __hip_atomic_store(&wp[s * 128 + t], pk, __ATOMIC_RELAXED,
                           __HIP_MEMORY_SCOPE_AGENT);
      }
    }
  }

  if (t < 128) Sbuf[(size_t)b * 512 + s * 128 + t] = Sreg;
}

// ---------------------------------------------------------------------------
// K7: epilogue  x = Minv * (alpha * A^T S - q)
// ---------------------------------------------------------------------------
__global__ __launch_bounds__(256) void k_final(
    const float* __restrict__ A, const float* __restrict__ q,
    const float* __restrict__ Mi, const float* __restrict__ Sbuf,
    float* __restrict__ xout) {
  int b = blockIdx.x, t = threadIdx.x;
  __shared__ float Ssh[512];
  __shared__ float uu[256];
  for (int i = t; i < 512; i += 256) Ssh[i] = Sbuf[(size_t)b * 512 + i];
  __syncthreads();
  const float* Ab = A + (size_t)b * 131072;
  float acc = 0.0f;
  for (int m = 0; m < 512; ++m) acc += Ab[(size_t)m * 256 + t] * Ssh[m];
  uu[t] = ALPHA_C * acc - q[(size_t)b * 256 + t];
  __syncthreads();
  const float* Mb = Mi + (size_t)b * 65536;
  float x = 0.0f;
  for (int kk = 0; kk < 256; ++kk) x += Mb[(size_t)kk * 256 + t] * uu[kk];
  xout[(size_t)b * 256 + t] = x;
}

// ---------------------------------------------------------------------------
// Workspace (float-slot offsets), all within the proven 29573120-slot span.
// Live-range reuse:
//   At   [0, 8388608)           steps 1-6
//   Fh   [0, 4194304)  Fe [4194304, 8388608)     step 9-10 (over dead At)
//   Mi   [8388608, 12582912)    step 4 -> end
//   Mk   [12582912, 16777216)   steps 3-4
//   Mih  [12582912, 14680064)  Mie [14680064, 16777216)  steps 8-9 (over Mk)
//   Gp   [12582912, 20971520)   step 10-11 (over dead Mih/Mie)
//   Ath  [20971520, 25165824)  Ate [25165824, 29360128)  steps 2-3
//   Ah   [20971520, 25165824)  Ae  [25165824, 29360128)  steps 7-10 (reuse)
//   hv/dv/Sbuf [29360128, 29442048); wtag [29442048, 29573120)
// ---------------------------------------------------------------------------
extern "C" void kernel_launch(void* const* d_in, const int* in_sizes, int n_in,
                              void* d_out, int out_size, void* d_ws, size_t ws_size,
                              hipStream_t stream) {
  (void)in_sizes; (void)n_in; (void)out_size; (void)ws_size;
  const float* P = (const float*)d_in[0];
  const float* q = (const float*)d_in[1];
  const float* Av = (const float*)d_in[2];
  const float* lv = (const float*)d_in[3];
  const float* uv = (const float*)d_in[4];
  float* xout = (float*)d_out;

  float* ws = (float*)d_ws;
  float* At = ws;
  float* Fh = ws;
  float* Fe = ws + 4194304;
  float* Mi = ws + 8388608;
  float* Mk = ws + 12582912;
  unsigned* Mih = (unsigned*)(ws + 12582912);
  unsigned* Mie = (unsigned*)(ws + 14680064);
  unsigned* Gp = (unsigned*)(ws + 12582912);
  unsigned* Ath = (unsigned*)(ws + 20971520);
  unsigned* Ate = (unsigned*)(ws + 25165824);
  unsigned* Ah = (unsigned*)(ws + 20971520);
  unsigned* Ae = (unsigned*)(ws + 25165824);
  float* hv = ws + 29360128;
  float* dv = ws + 29376512;
  float* Sbuf = ws + 29409280;
  unsigned long long* wtag = (unsigned long long*)(ws + 29442048);

  hipMemsetAsync(wtag, 0, 524288, stream);  // scrub stale tags

  // 1) At = A^T
  k_transpose<<<dim3(8, 16, 64), dim3(32, 8), 0, stream>>>(Av, At);
  // 2) split-cast At
  k_cast_split<<<8192, 256, 0, stream>>>(At, Ath, Ate, 2097152);
  // 3) Mk = rho*A^T A + diag(P)+sigma  (split-MFMA NT on At rows, K=512)
  k_mfma_nt<<<dim3(16, 64), 256, 0, stream>>>(
      (const _Float16*)Ath, (const _Float16*)Ate,
      (const _Float16*)Ath, (const _Float16*)Ate,
      Mk, nullptr, 512, 2, 131072LL, 131072LL, 65536LL, RHO_C, P, 0);
  // 4) Mi = Mk^-1
  k_invert<<<64, 512, 0, stream>>>(Mk, Mi);
  // 5) h = Mi q ; 6) d = A h
  k_matvec_h<<<64, 256, 0, stream>>>(Mi, q, hv);
  k_matvec_d<<<64, 512, 0, stream>>>(At, hv, dv);
  // 7) split-cast Av (over dead Ath/Ate)
  k_cast_split<<<8192, 256, 0, stream>>>(Av, Ah, Ae, 2097152);
  // 8) split-cast Mi (over dead Mk)
  k_cast_split<<<4096, 256, 0, stream>>>(Mi, Mih, Mie, 1048576);
  // 9) F = A*Mi (Mi symmetric -> NT; split-MFMA, split-fp16 out, over dead At)
  k_mfma_nt<<<dim3(32, 64), 256, 0, stream>>>(
      (const _Float16*)Ah, (const _Float16*)Ae,
      (const _Float16*)Mih, (const _Float16*)Mie,
      Fh, Fe, 256, 2, 131072LL, 65536LL, 131072LL, 1.0f, nullptr, 1);
  // 10) G = F*A^T (round-9 proven), packed output over dead Mih/Mie
  k_mfma_g<<<dim3(64, 64), 256, 0, stream>>>(
      (const _Float16*)Fh, (const _Float16*)Fe,
      (const _Float16*)Ah, (const _Float16*)Ae, Gp);
  // 11) ADMM loop (round-7 frozen)
  k_admm4<<<256, 512, 0, stream>>>(Gp, dv, lv, uv, wtag, Sbuf);
  // 12) epilogue
  k_final<<<64, 256, 0, stream>>>(Av, q, Mi, Sbuf, xout);
}